// Round 1
// baseline (386.801 us; speedup 1.0000x reference)
//
#include <hip/hip_runtime.h>
#include <stdint.h>

typedef unsigned short u16;
typedef float f32x4 __attribute__((ext_vector_type(4)));
typedef __bf16 bf16x8 __attribute__((ext_vector_type(8)));

#define B_ 4096
#define D_ 2048
#define U_ 2048
#define K_ 4096   // D + U
#define N_ 8192   // 4*U
#define BM 128
#define BN 128
#define BK 32

__device__ __forceinline__ u16 f32_bf16(float f) {
  uint32_t u = __float_as_uint(f);
  u += 0x7FFFu + ((u >> 16) & 1u);   // round-to-nearest-even
  return (u16)(u >> 16);
}

__device__ __forceinline__ float hsig(float x) {
  return fminf(fmaxf(0.2f * x + 0.5f, 0.0f), 1.0f);
}

__device__ __forceinline__ float ftanh(float x) {
  x = fminf(fmaxf(x, -15.0f), 15.0f);
  float e = __expf(2.0f * x);
  return (e - 1.0f) / (e + 1.0f);
}

__device__ __forceinline__ void gload16(const void* g, void* l) {
  __builtin_amdgcn_global_load_lds(
      (const __attribute__((address_space(1))) void*)g,
      (__attribute__((address_space(3))) void*)l,
      16, 0, 0);
}

// ---- cast A = [inputs | h_tm1] -> bf16 [4096][4096] ----
__global__ __launch_bounds__(256) void cast_a(const float* __restrict__ x,
                                              const float* __restrict__ h,
                                              u16* __restrict__ A) {
  int c = blockIdx.x * 256 + threadIdx.x;       // 2M chunks of 8 elems
  int m = c >> 9;                                // 512 chunks per row
  int kc = (c & 511) << 3;
  const float* src = (kc < D_) ? (x + (size_t)m * D_ + kc)
                               : (h + (size_t)m * U_ + (kc - D_));
  float4 v0 = ((const float4*)src)[0];
  float4 v1 = ((const float4*)src)[1];
  u16 o[8] = { f32_bf16(v0.x), f32_bf16(v0.y), f32_bf16(v0.z), f32_bf16(v0.w),
               f32_bf16(v1.x), f32_bf16(v1.y), f32_bf16(v1.z), f32_bf16(v1.w) };
  *(uint4*)(A + (size_t)c * 8) = *(const uint4*)o;
}

// ---- cast + transpose + gate-interleave W -> Wt[n'][k] bf16 [8192][4096] ----
// n' = ublk*64 + g*16 + ul  where original col n = g*2048 + ublk*16 + ul
__global__ __launch_bounds__(256) void cast_wt(const float* __restrict__ kern,
                                               const float* __restrict__ rker,
                                               u16* __restrict__ Wt) {
  __shared__ u16 sW[64][68];
  const int t = threadIdx.x;
  const int bx = blockIdx.x;   // ublk 0..127  (n' block of 64)
  const int by = blockIdx.y;   // k block 0..63
  const int k0 = by * 64;
  const float* src = (k0 < D_) ? kern : rker;
  const int krow0 = (k0 < D_) ? k0 : (k0 - D_);
#pragma unroll
  for (int i = 0; i < 4; ++i) {
    int c = i * 256 + t;
    int kl = c >> 4;           // 0..63 local k row
    int nq = c & 15;           // quad of n'
    int g  = nq >> 2;
    int ul = (nq & 3) << 2;
    int n  = g * U_ + bx * 16 + ul;
    float4 v = *(const float4*)(src + (size_t)(krow0 + kl) * N_ + n);
    u16 p[4] = { f32_bf16(v.x), f32_bf16(v.y), f32_bf16(v.z), f32_bf16(v.w) };
    *(ushort4*)&sW[kl][g * 16 + ul] = *(const ushort4*)p;
  }
  __syncthreads();
#pragma unroll
  for (int j = 0; j < 2; ++j) {
    int c2 = j * 256 + t;
    int nl = c2 >> 3;          // 0..63 local n'
    int kc = c2 & 7;           // 8-elem chunk along k
    u16 p[8];
#pragma unroll
    for (int jj = 0; jj < 8; ++jj) p[jj] = sW[kc * 8 + jj][nl];
    *(uint4*)(Wt + ((size_t)bx * 64 + nl) * K_ + k0 + kc * 8) = *(const uint4*)p;
  }
}

// ---- fused GEMM + LSTM epilogue ----
// Z[m][n'] = sum_k A[m][k] * Wt[n'][k]; per-wave cols = 4 gates x 16 u
__global__ __launch_bounds__(256) void lstm_gemm(const u16* __restrict__ A,
                                                 const u16* __restrict__ Wt,
                                                 const float* __restrict__ c_prev,
                                                 float* __restrict__ out) {
  __shared__ __align__(16) u16 lA[BM * BK];
  __shared__ __align__(16) u16 lB[BN * BK];
  const int tid  = threadIdx.x;
  const int lane = tid & 63;
  const int wid  = tid >> 6;
  const int wr   = wid >> 1;   // wave row 0..1 (64 rows each)
  const int wc   = wid & 1;    // wave col 0..1 (64 cols each)
  const int bm   = blockIdx.y;
  const int bn   = blockIdx.x;

  f32x4 acc[4][4] = {};        // acc[m][gate]

  const u16* Ab = A  + (size_t)bm * BM * K_;
  const u16* Bb = Wt + (size_t)bn * BN * K_;

  const int row0 = tid >> 2;           // staging row (chunk r=0)
  const int kc0  = (tid & 3) * 8;      // staging k offset (elems)
  char* lAb = (char*)lA + (size_t)wid * 1024;
  char* lBb = (char*)lB + (size_t)wid * 1024;

  const int fr = lane & 15;            // fragment row/col index
  const int fq = lane >> 4;            // k-quad / row-quad index

  for (int kt = 0; kt < K_ / BK; ++kt) {
    const int ko = kt * BK;
    gload16(Ab + (size_t)row0 * K_ + ko + kc0,        lAb);
    gload16(Ab + (size_t)(row0 + 64) * K_ + ko + kc0, lAb + 4096);
    gload16(Bb + (size_t)row0 * K_ + ko + kc0,        lBb);
    gload16(Bb + (size_t)(row0 + 64) * K_ + ko + kc0, lBb + 4096);
    __syncthreads();

    bf16x8 af[4], bfr[4];
#pragma unroll
    for (int m = 0; m < 4; ++m) {
      int row = wr * 64 + m * 16 + fr;
      af[m] = *(const bf16x8*)&lA[row * BK + fq * 8];
    }
#pragma unroll
    for (int g = 0; g < 4; ++g) {
      int col = wc * 64 + g * 16 + fr;
      bfr[g] = *(const bf16x8*)&lB[col * BK + fq * 8];
    }
#pragma unroll
    for (int m = 0; m < 4; ++m)
#pragma unroll
      for (int g = 0; g < 4; ++g)
        acc[m][g] = __builtin_amdgcn_mfma_f32_16x16x32_bf16(af[m], bfr[g],
                                                            acc[m][g], 0, 0, 0);
    __syncthreads();
  }

  // epilogue: this wave owns u-block ub (16 u's) x 64 rows, all 4 gates
  const int ub = bn * 2 + wc;
  const int u  = ub * 16 + fr;
  const size_t BU = (size_t)B_ * U_;
#pragma unroll
  for (int m = 0; m < 4; ++m) {
#pragma unroll
    for (int r = 0; r < 4; ++r) {
      int grow = bm * BM + wr * 64 + m * 16 + fq * 4 + r;
      float zi = acc[m][0][r], zf = acc[m][1][r];
      float zc = acc[m][2][r], zo = acc[m][3][r];
      float iv = hsig(zi), fv = hsig(zf), ov = hsig(zo);
      size_t off = (size_t)grow * U_ + u;
      float cp = c_prev[off];
      float cv = fv * cp + iv * ftanh(zc);
      float hv = ov * ftanh(cv);
      out[off]          = hv;
      out[BU + off]     = hv;
      out[2 * BU + off] = cv;
    }
  }
}

extern "C" void kernel_launch(void* const* d_in, const int* in_sizes, int n_in,
                              void* d_out, int out_size, void* d_ws, size_t ws_size,
                              hipStream_t stream) {
  const float* x  = (const float*)d_in[0];
  const float* h  = (const float*)d_in[1];
  const float* cp = (const float*)d_in[2];
  const float* kk = (const float*)d_in[3];
  const float* rk = (const float*)d_in[4];
  float* out = (float*)d_out;

  const size_t bytesA  = (size_t)B_ * K_ * 2;   // 32 MiB
  const size_t bytesWt = (size_t)N_ * K_ * 2;   // 64 MiB
  if (ws_size < bytesA + bytesWt) return;       // fail visibly, don't corrupt

  u16* Aws = (u16*)d_ws;
  u16* Wt  = (u16*)((char*)d_ws + bytesA);

  cast_a<<<(B_ * K_ / 8) / 256, 256, 0, stream>>>(x, h, Aws);
  cast_wt<<<dim3(N_ / 64, K_ / 64), 256, 0, stream>>>(kk, rk, Wt);
  lstm_gemm<<<dim3(N_ / BN, B_ / BM), 256, 0, stream>>>(Aws, Wt, cp, out);
}

// Round 2
// 322.950 us; speedup vs baseline: 1.1977x; 1.1977x over previous
//
#include <hip/hip_runtime.h>
#include <stdint.h>

typedef unsigned short u16;
typedef float f32x4 __attribute__((ext_vector_type(4)));
typedef __bf16 bf16x8 __attribute__((ext_vector_type(8)));

#define B_ 4096
#define D_ 2048
#define U_ 2048
#define K_ 4096   // D + U
#define N_ 8192   // 4*U
#define NIT 32    // K / (2*64): 2 K-tiles (BK=64) per iteration

__device__ __forceinline__ u16 f32_bf16(float f) {
  uint32_t u = __float_as_uint(f);
  u += 0x7FFFu + ((u >> 16) & 1u);
  return (u16)(u >> 16);
}
__device__ __forceinline__ float hsig(float x) {
  return fminf(fmaxf(0.2f * x + 0.5f, 0.0f), 1.0f);
}
__device__ __forceinline__ float ftanh(float x) {
  x = fminf(fmaxf(x, -15.0f), 15.0f);
  float e = __expf(2.0f * x);
  return (e - 1.0f) / (e + 1.0f);
}
__device__ __forceinline__ void gload16(const void* g, void* l) {
  __builtin_amdgcn_global_load_lds(
      (const __attribute__((address_space(1))) void*)g,
      (__attribute__((address_space(3))) void*)l,
      16, 0, 0);
}

// ---- cast A = [inputs | h_tm1] -> bf16 [4096][4096] ----
__global__ __launch_bounds__(256) void cast_a(const float* __restrict__ x,
                                              const float* __restrict__ h,
                                              u16* __restrict__ A) {
  int c = blockIdx.x * 256 + threadIdx.x;
  int m = c >> 9;
  int kc = (c & 511) << 3;
  const float* src = (kc < D_) ? (x + (size_t)m * D_ + kc)
                               : (h + (size_t)m * U_ + (kc - D_));
  float4 v0 = ((const float4*)src)[0];
  float4 v1 = ((const float4*)src)[1];
  u16 o[8] = { f32_bf16(v0.x), f32_bf16(v0.y), f32_bf16(v0.z), f32_bf16(v0.w),
               f32_bf16(v1.x), f32_bf16(v1.y), f32_bf16(v1.z), f32_bf16(v1.w) };
  *(uint4*)(A + (size_t)c * 8) = *(const uint4*)o;
}

// ---- cast + transpose + gate-interleave W -> Wt[n'][k] bf16 [8192][4096] ----
// n' = ublk*64 + g*16 + ul  where original col n = g*2048 + ublk*16 + ul
__global__ __launch_bounds__(256) void cast_wt(const float* __restrict__ kern,
                                               const float* __restrict__ rker,
                                               u16* __restrict__ Wt) {
  __shared__ u16 sW[64][68];
  const int t = threadIdx.x;
  const int bx = blockIdx.x;
  const int by = blockIdx.y;
  const int k0 = by * 64;
  const float* src = (k0 < D_) ? kern : rker;
  const int krow0 = (k0 < D_) ? k0 : (k0 - D_);
#pragma unroll
  for (int i = 0; i < 4; ++i) {
    int c = i * 256 + t;
    int kl = c >> 4;
    int nq = c & 15;
    int g  = nq >> 2;
    int ul = (nq & 3) << 2;
    int n  = g * U_ + bx * 16 + ul;
    float4 v = *(const float4*)(src + (size_t)(krow0 + kl) * N_ + n);
    u16 p[4] = { f32_bf16(v.x), f32_bf16(v.y), f32_bf16(v.z), f32_bf16(v.w) };
    *(ushort4*)&sW[kl][g * 16 + ul] = *(const ushort4*)p;
  }
  __syncthreads();
#pragma unroll
  for (int j = 0; j < 2; ++j) {
    int c2 = j * 256 + t;
    int nl = c2 >> 3;
    int kc = c2 & 7;
    u16 p[8];
#pragma unroll
    for (int jj = 0; jj < 8; ++jj) p[jj] = sW[kc * 8 + jj][nl];
    *(uint4*)(Wt + ((size_t)bx * 64 + nl) * K_ + k0 + kc * 8) = *(const uint4*)p;
  }
}

// ================= 256x256 8-phase GEMM + fused LSTM epilogue =================
// LDS layout (bytes): [parity][A=0/B=1][khalf][256 rows][32 elems] ; 128 KiB.
// Half-buffer row stride 64B; 16B chunk swizzled: phys_chunk = logical ^ (row&3).
#define ABASE(par, kk) ((par) * 65536 + (kk) * 16384)
#define BBASE(par, kk) ((par) * 65536 + 32768 + (kk) * 16384)

#define STAGE_A(par, kk, t) do { \
  const u16* gp_ = Ab + (size_t)grow * K_ + (t) * 64 + (kk) * 32 + gch8; \
  char* lp_ = ldsc + ABASE(par, kk) + wid * 1024; \
  gload16(gp_, lp_); \
  gload16(gp_ + (size_t)128 * K_, lp_ + 8192); \
} while (0)

#define STAGE_B(par, kk, t) do { \
  const u16* gp_ = Bb + (size_t)grow * K_ + (t) * 64 + (kk) * 32 + gch8; \
  char* lp_ = ldsc + BBASE(par, kk) + wid * 1024; \
  gload16(gp_, lp_); \
  gload16(gp_ + (size_t)128 * K_, lp_ + 8192); \
} while (0)

#define VMW(n) asm volatile("s_waitcnt vmcnt(" #n ")" ::: "memory")

#define MFMA16(mh) do { \
  _Pragma("unroll") \
  for (int m_ = 0; m_ < 4; ++m_) { \
    _Pragma("unroll") \
    for (int n_ = 0; n_ < 4; ++n_) \
      acc[(mh) * 4 + m_][n_] = __builtin_amdgcn_mfma_f32_16x16x32_bf16( \
          av[m_], bv[n_], acc[(mh) * 4 + m_][n_], 0, 0, 0); \
  } \
} while (0)

#define PHASE(par, kk, mh, RB, STAGE_STMT, TAIL_STMT) do { \
  const char* pab_ = ldsc + ABASE(par, kk); \
  _Pragma("unroll") \
  for (int m_ = 0; m_ < 4; ++m_) \
    av[m_] = *(const bf16x8*)(pab_ + aoff + (mh) * 4096 + m_ * 1024); \
  if (RB) { \
    const char* pbb_ = ldsc + BBASE(par, kk); \
    _Pragma("unroll") \
    for (int n_ = 0; n_ < 4; ++n_) \
      bv[n_] = *(const bf16x8*)(pbb_ + boff + n_ * 1024); \
  } \
  STAGE_STMT; \
  __builtin_amdgcn_s_barrier(); \
  asm volatile("s_waitcnt lgkmcnt(0)" ::: "memory"); \
  __builtin_amdgcn_s_setprio(1); \
  MFMA16(mh); \
  __builtin_amdgcn_s_setprio(0); \
  TAIL_STMT; \
  __builtin_amdgcn_s_barrier(); \
} while (0)

__global__ __launch_bounds__(512, 2) void lstm_gemm(const u16* __restrict__ A,
                                                    const u16* __restrict__ Wt,
                                                    const float* __restrict__ c_prev,
                                                    float* __restrict__ out) {
  __shared__ __align__(16) u16 lds[65536];   // 128 KiB
  char* ldsc = (char*)lds;
  const int tid  = threadIdx.x;
  const int lane = tid & 63;
  const int wid  = tid >> 6;
  const int wr   = wid >> 2;   // 0..1: 128-row half
  const int wcn  = wid & 3;    // 0..3: 64-col slice
  const int fr   = lane & 15;
  const int fq   = lane >> 4;

  // XCD-aware swizzle (512 % 8 == 0 -> simple form is bijective)
  const int orig = blockIdx.x;
  const int wg   = ((orig & 7) << 6) | (orig >> 3);
  const int bm   = wg & 15;    // fastest: consecutive blocks on an XCD share bn's B-panel
  const int bn   = wg >> 4;

  const u16* Ab = A  + (size_t)bm * 256 * K_;
  const u16* Bb = Wt + (size_t)bn * 256 * K_;

  // staging: thread -> (row, swizzled 16B chunk) of a [256][32] half-tile
  const int grow = tid >> 2;
  const int gch8 = (((tid & 3) ^ (grow & 3)) << 3);   // element offset
  // reads: swizzled chunk is fq ^ (fr&3) since row % 4 == fr % 4
  const int csw  = (fq ^ (fr & 3)) << 4;
  const int aoff = (wr * 128 + fr) * 64 + csw;        // + mh*4096 + m*1024
  const int boff = (wcn * 64 + fr) * 64 + csw;        // + n*1024

  f32x4 acc[8][4] = {};
  bf16x8 av[4], bv[4];

  // ---- prologue: tile0 (par0) fully + tile1 (par1) k0 ----
  STAGE_A(0, 0, 0);
  STAGE_B(0, 0, 0);
  STAGE_A(0, 1, 0);
  STAGE_B(0, 1, 0);
  STAGE_A(1, 0, 1);
  STAGE_B(1, 0, 1);
  VMW(4);                       // tile0 landed; tile1-k0 in flight
  __builtin_amdgcn_s_barrier();

  for (int i = 0; i < NIT; ++i) {
    const int t1 = 2 * i + 1;
    const int t2 = 2 * i + 2;
    const int t3 = 2 * i + 3;
    const bool nl = (i + 1 < NIT);
    // tile t0 = 2i from parity 0
    PHASE(0, 0, 0, 1, { STAGE_A(1, 1, t1); }, {});
    PHASE(0, 0, 1, 0, { STAGE_B(1, 1, t1); }, {});
    PHASE(0, 1, 0, 1, { if (nl) STAGE_A(0, 0, t2); }, {});
    PHASE(0, 1, 1, 0, { if (nl) STAGE_B(0, 0, t2); },
          { if (nl) { VMW(4); } else { VMW(0); } });
    // tile t1 = 2i+1 from parity 1
    PHASE(1, 0, 0, 1, { if (nl) STAGE_A(0, 1, t2); }, {});
    PHASE(1, 0, 1, 0, { if (nl) STAGE_B(0, 1, t2); }, {});
    PHASE(1, 1, 0, 1, { if (nl) STAGE_A(1, 0, t3); }, {});
    PHASE(1, 1, 1, 0, { if (nl) STAGE_B(1, 0, t3); }, { VMW(4); });
  }

  // ---- fused LSTM epilogue ----
  const int u  = (bn * 4 + wcn) * 16 + fr;
  const size_t BU = (size_t)B_ * U_;
#pragma unroll
  for (int mi = 0; mi < 8; ++mi) {
#pragma unroll
    for (int r = 0; r < 4; ++r) {
      int row = bm * 256 + wr * 128 + mi * 16 + fq * 4 + r;
      float zi = acc[mi][0][r], zf = acc[mi][1][r];
      float zc = acc[mi][2][r], zo = acc[mi][3][r];
      float iv = hsig(zi), fv = hsig(zf), ov = hsig(zo);
      size_t off = (size_t)row * U_ + u;
      float cp = c_prev[off];
      float cv = fv * cp + iv * ftanh(zc);
      float hv = ov * ftanh(cv);
      out[off]          = hv;
      out[BU + off]     = hv;
      out[2 * BU + off] = cv;
    }
  }
}

extern "C" void kernel_launch(void* const* d_in, const int* in_sizes, int n_in,
                              void* d_out, int out_size, void* d_ws, size_t ws_size,
                              hipStream_t stream) {
  const float* x  = (const float*)d_in[0];
  const float* h  = (const float*)d_in[1];
  const float* cp = (const float*)d_in[2];
  const float* kk = (const float*)d_in[3];
  const float* rk = (const float*)d_in[4];
  float* out = (float*)d_out;

  const size_t bytesA  = (size_t)B_ * K_ * 2;   // 32 MiB
  const size_t bytesWt = (size_t)N_ * K_ * 2;   // 64 MiB
  if (ws_size < bytesA + bytesWt) return;

  u16* Aws = (u16*)d_ws;
  u16* Wt  = (u16*)((char*)d_ws + bytesA);

  cast_a<<<(B_ * K_ / 8) / 256, 256, 0, stream>>>(x, h, Aws);
  cast_wt<<<dim3(N_ / 64, K_ / 64), 256, 0, stream>>>(kk, rk, Wt);
  lstm_gemm<<<dim3(512), dim3(512), 0, stream>>>(Aws, Wt, cp, out);
}

// Round 3
// 309.684 us; speedup vs baseline: 1.2490x; 1.0428x over previous
//
#include <hip/hip_runtime.h>
#include <stdint.h>

typedef unsigned short u16;
typedef float f32x4 __attribute__((ext_vector_type(4)));
typedef __bf16 bf16x8 __attribute__((ext_vector_type(8)));

#define B_ 4096
#define D_ 2048
#define U_ 2048
#define K_ 4096   // D + U
#define N_ 8192   // 4*U
#define NIT 32    // K / (2*64): 2 K-tiles (BK=64) per iteration

__device__ __forceinline__ u16 f32_bf16(float f) {
  uint32_t u = __float_as_uint(f);
  u += 0x7FFFu + ((u >> 16) & 1u);
  return (u16)(u >> 16);
}
__device__ __forceinline__ float hsig(float x) {
  return fminf(fmaxf(0.2f * x + 0.5f, 0.0f), 1.0f);
}
__device__ __forceinline__ float ftanh(float x) {
  x = fminf(fmaxf(x, -15.0f), 15.0f);
  float e = __expf(2.0f * x);
  return (e - 1.0f) / (e + 1.0f);
}
__device__ __forceinline__ void gload16(const void* g, void* l) {
  __builtin_amdgcn_global_load_lds(
      (const __attribute__((address_space(1))) void*)g,
      (__attribute__((address_space(3))) void*)l,
      16, 0, 0);
}

// ---- cast A = [inputs | h_tm1] -> bf16 [4096][4096] ----
__global__ __launch_bounds__(256) void cast_a(const float* __restrict__ x,
                                              const float* __restrict__ h,
                                              u16* __restrict__ A) {
  int c = blockIdx.x * 256 + threadIdx.x;
  int m = c >> 9;
  int kc = (c & 511) << 3;
  const float* src = (kc < D_) ? (x + (size_t)m * D_ + kc)
                               : (h + (size_t)m * U_ + (kc - D_));
  float4 v0 = ((const float4*)src)[0];
  float4 v1 = ((const float4*)src)[1];
  u16 o[8] = { f32_bf16(v0.x), f32_bf16(v0.y), f32_bf16(v0.z), f32_bf16(v0.w),
               f32_bf16(v1.x), f32_bf16(v1.y), f32_bf16(v1.z), f32_bf16(v1.w) };
  *(uint4*)(A + (size_t)c * 8) = *(const uint4*)o;
}

// ---- cast + transpose + gate-interleave W -> Wt[n'][k] bf16 [8192][4096] ----
// n' = ublk*64 + g*16 + ul  where original col n = g*2048 + ublk*16 + ul
__global__ __launch_bounds__(256) void cast_wt(const float* __restrict__ kern,
                                               const float* __restrict__ rker,
                                               u16* __restrict__ Wt) {
  __shared__ u16 sW[64][68];
  const int t = threadIdx.x;
  const int bx = blockIdx.x;
  const int by = blockIdx.y;
  const int k0 = by * 64;
  const float* src = (k0 < D_) ? kern : rker;
  const int krow0 = (k0 < D_) ? k0 : (k0 - D_);
#pragma unroll
  for (int i = 0; i < 4; ++i) {
    int c = i * 256 + t;
    int kl = c >> 4;
    int nq = c & 15;
    int g  = nq >> 2;
    int ul = (nq & 3) << 2;
    int n  = g * U_ + bx * 16 + ul;
    float4 v = *(const float4*)(src + (size_t)(krow0 + kl) * N_ + n);
    u16 p[4] = { f32_bf16(v.x), f32_bf16(v.y), f32_bf16(v.z), f32_bf16(v.w) };
    *(ushort4*)&sW[kl][g * 16 + ul] = *(const ushort4*)p;
  }
  __syncthreads();
#pragma unroll
  for (int j = 0; j < 2; ++j) {
    int c2 = j * 256 + t;
    int nl = c2 >> 3;
    int kc = c2 & 7;
    u16 p[8];
#pragma unroll
    for (int jj = 0; jj < 8; ++jj) p[jj] = sW[kc * 8 + jj][nl];
    *(uint4*)(Wt + ((size_t)bx * 64 + nl) * K_ + k0 + kc * 8) = *(const uint4*)p;
  }
}

// ================= 256x256 8-phase GEMM + fused LSTM epilogue =================
// LDS layout (bytes): [parity][A=0/B=1][khalf][256 rows][32 elems] ; 128 KiB.
// Half-buffer row stride 64B; 16B chunk swizzled: phys_chunk = logical ^ ((row>>1)&3).
// (row>>1)&3 spreads chunks over all 4 values within BOTH even and odd row
// classes -> (row&1, chunk) covers all 8 bank-groups 2x per 16-lane quad.
#define ABASE(par, kk) ((par) * 65536 + (kk) * 16384)
#define BBASE(par, kk) ((par) * 65536 + 32768 + (kk) * 16384)

#define STAGE_A(par, kk, t) do { \
  const u16* gp_ = Ab + (size_t)grow * K_ + (t) * 64 + (kk) * 32 + gch8; \
  char* lp_ = ldsc + ABASE(par, kk) + wid * 1024; \
  gload16(gp_, lp_); \
  gload16(gp_ + (size_t)128 * K_, lp_ + 8192); \
} while (0)

#define STAGE_B(par, kk, t) do { \
  const u16* gp_ = Bb + (size_t)grow * K_ + (t) * 64 + (kk) * 32 + gch8; \
  char* lp_ = ldsc + BBASE(par, kk) + wid * 1024; \
  gload16(gp_, lp_); \
  gload16(gp_ + (size_t)128 * K_, lp_ + 8192); \
} while (0)

#define VMW(n) asm volatile("s_waitcnt vmcnt(" #n ")" ::: "memory")

#define MFMA16(mh) do { \
  _Pragma("unroll") \
  for (int m_ = 0; m_ < 4; ++m_) { \
    _Pragma("unroll") \
    for (int n_ = 0; n_ < 4; ++n_) \
      acc[(mh) * 4 + m_][n_] = __builtin_amdgcn_mfma_f32_16x16x32_bf16( \
          av[m_], bv[n_], acc[(mh) * 4 + m_][n_], 0, 0, 0); \
  } \
} while (0)

#define PHASE(par, kk, mh, RB, STAGE_STMT, TAIL_STMT) do { \
  const char* pab_ = ldsc + ABASE(par, kk); \
  _Pragma("unroll") \
  for (int m_ = 0; m_ < 4; ++m_) \
    av[m_] = *(const bf16x8*)(pab_ + aoff + (mh) * 4096 + m_ * 1024); \
  if (RB) { \
    const char* pbb_ = ldsc + BBASE(par, kk); \
    _Pragma("unroll") \
    for (int n_ = 0; n_ < 4; ++n_) \
      bv[n_] = *(const bf16x8*)(pbb_ + boff + n_ * 1024); \
  } \
  STAGE_STMT; \
  __builtin_amdgcn_s_barrier(); \
  asm volatile("s_waitcnt lgkmcnt(0)" ::: "memory"); \
  __builtin_amdgcn_s_setprio(1); \
  MFMA16(mh); \
  __builtin_amdgcn_s_setprio(0); \
  TAIL_STMT; \
  __builtin_amdgcn_s_barrier(); \
} while (0)

__global__ __launch_bounds__(512, 2) void lstm_gemm(const u16* __restrict__ A,
                                                    const u16* __restrict__ Wt,
                                                    const float* __restrict__ c_prev,
                                                    float* __restrict__ out) {
  __shared__ __align__(16) u16 lds[65536];   // 128 KiB
  char* ldsc = (char*)lds;
  const int tid  = threadIdx.x;
  const int lane = tid & 63;
  const int wid  = tid >> 6;
  const int wr   = wid >> 2;   // 0..1: 128-row half
  const int wcn  = wid & 3;    // 0..3: 64-col slice
  const int fr   = lane & 15;
  const int fq   = lane >> 4;

  // XCD-aware swizzle (512 % 8 == 0 -> simple form is bijective)
  const int orig = blockIdx.x;
  const int wg   = ((orig & 7) << 6) | (orig >> 3);
  const int bm   = wg & 15;    // fastest: consecutive blocks on an XCD share bn's B-panel
  const int bn   = wg >> 4;

  const u16* Ab = A  + (size_t)bm * 256 * K_;
  const u16* Bb = Wt + (size_t)bn * 256 * K_;

  // staging: thread -> (row, swizzled 16B chunk) of a [256][32] half-tile
  const int grow = tid >> 2;
  const int gch8 = (((tid & 3) ^ ((grow >> 1) & 3)) << 3);   // element offset
  // reads: swizzled chunk is fq ^ ((fr>>1)&3) since row bits 1..3 == fr bits 1..3
  const int csw  = (fq ^ ((fr >> 1) & 3)) << 4;
  const int aoff = (wr * 128 + fr) * 64 + csw;        // + mh*4096 + m*1024
  const int boff = (wcn * 64 + fr) * 64 + csw;        // + n*1024

  f32x4 acc[8][4] = {};
  bf16x8 av[4], bv[4];

  // ---- prologue: tile0 (par0) fully + tile1 (par1) k0 ----
  STAGE_A(0, 0, 0);
  STAGE_B(0, 0, 0);
  STAGE_A(0, 1, 0);
  STAGE_B(0, 1, 0);
  STAGE_A(1, 0, 1);
  STAGE_B(1, 0, 1);
  VMW(4);                       // tile0 landed; tile1-k0 in flight
  __builtin_amdgcn_s_barrier();

  for (int i = 0; i < NIT; ++i) {
    const int t1 = 2 * i + 1;
    const int t2 = 2 * i + 2;
    const int t3 = 2 * i + 3;
    const bool nl = (i + 1 < NIT);
    // tile t0 = 2i from parity 0
    PHASE(0, 0, 0, 1, { STAGE_A(1, 1, t1); }, {});
    PHASE(0, 0, 1, 0, { STAGE_B(1, 1, t1); }, {});
    PHASE(0, 1, 0, 1, { if (nl) STAGE_A(0, 0, t2); }, {});
    PHASE(0, 1, 1, 0, { if (nl) STAGE_B(0, 0, t2); },
          { if (nl) { VMW(4); } else { VMW(0); } });
    // tile t1 = 2i+1 from parity 1
    PHASE(1, 0, 0, 1, { if (nl) STAGE_A(0, 1, t2); }, {});
    PHASE(1, 0, 1, 0, { if (nl) STAGE_B(0, 1, t2); }, {});
    PHASE(1, 1, 0, 1, { if (nl) STAGE_A(1, 0, t3); }, {});
    PHASE(1, 1, 1, 0, { if (nl) STAGE_B(1, 0, t3); }, { VMW(4); });
  }

  // ---- fused LSTM epilogue ----
  const int u  = (bn * 4 + wcn) * 16 + fr;
  const size_t BU = (size_t)B_ * U_;
#pragma unroll
  for (int mi = 0; mi < 8; ++mi) {
#pragma unroll
    for (int r = 0; r < 4; ++r) {
      int row = bm * 256 + wr * 128 + mi * 16 + fq * 4 + r;
      float zi = acc[mi][0][r], zf = acc[mi][1][r];
      float zc = acc[mi][2][r], zo = acc[mi][3][r];
      float iv = hsig(zi), fv = hsig(zf), ov = hsig(zo);
      size_t off = (size_t)row * U_ + u;
      float cp = c_prev[off];
      float cv = fv * cp + iv * ftanh(zc);
      float hv = ov * ftanh(cv);
      out[off]          = hv;
      out[BU + off]     = hv;
      out[2 * BU + off] = cv;
    }
  }
}

extern "C" void kernel_launch(void* const* d_in, const int* in_sizes, int n_in,
                              void* d_out, int out_size, void* d_ws, size_t ws_size,
                              hipStream_t stream) {
  const float* x  = (const float*)d_in[0];
  const float* h  = (const float*)d_in[1];
  const float* cp = (const float*)d_in[2];
  const float* kk = (const float*)d_in[3];
  const float* rk = (const float*)d_in[4];
  float* out = (float*)d_out;

  const size_t bytesA  = (size_t)B_ * K_ * 2;   // 32 MiB
  const size_t bytesWt = (size_t)N_ * K_ * 2;   // 64 MiB
  if (ws_size < bytesA + bytesWt) return;

  u16* Aws = (u16*)d_ws;
  u16* Wt  = (u16*)((char*)d_ws + bytesA);

  cast_a<<<(B_ * K_ / 8) / 256, 256, 0, stream>>>(x, h, Aws);
  cast_wt<<<dim3(N_ / 64, K_ / 64), 256, 0, stream>>>(kk, rk, Wt);
  lstm_gemm<<<dim3(512), dim3(512), 0, stream>>>(Aws, Wt, cp, out);
}